// Round 3
// baseline (368.390 us; speedup 1.0000x reference)
//
#include <hip/hip_runtime.h>
#include <string.h>

#define H 128
#define NTYPES 28
#define CNT_BYTES_PER_CYCLE 32   // 28 byte counters + 4 pad, dword-packed

typedef float f32x4 __attribute__((ext_vector_type(4)));

// ---- count: one incidence -> +1 on byte counter cnt[cycle][type] ----
// 4 incidences per thread, int4 loads on both index rows. Fire-and-forget
// 32-bit atomics (no return value -> no serialization chain); ~87 us at the
// device scattered-atomic rate (R0/R1/R2 cross-arithmetic). Binned variant
// with returning atomics measured 416 us in R1 -- do not revisit.
__global__ void count_kernel(const int* __restrict__ a2c,
                             const int* __restrict__ x,
                             unsigned* __restrict__ cnt,
                             int n_inc) {
    int i = (blockIdx.x * blockDim.x + threadIdx.x) * 4;
    if (i + 3 < n_inc) {
        int4 at = *(const int4*)(a2c + i);
        int4 cy = *(const int4*)(a2c + n_inc + i);
        int t0 = x[at.x], t1 = x[at.y], t2 = x[at.z], t3 = x[at.w];
        atomicAdd(&cnt[cy.x * 8 + (t0 >> 2)], 1u << (8 * (t0 & 3)));
        atomicAdd(&cnt[cy.y * 8 + (t1 >> 2)], 1u << (8 * (t1 & 3)));
        atomicAdd(&cnt[cy.z * 8 + (t2 >> 2)], 1u << (8 * (t2 & 3)));
        atomicAdd(&cnt[cy.w * 8 + (t3 >> 2)], 1u << (8 * (t3 & 3)));
    } else {
        for (int e = i; e < n_inc; ++e) {
            int atom = a2c[e];
            int cycv = a2c[n_inc + e];
            int t = x[atom];
            atomicAdd(&cnt[cycv * 8 + (t >> 2)], 1u << (8 * (t & 3)));
        }
    }
}

// ---- expand2: one wave per PAIR of cycles, contiguous chunks ----
// lanes 0-31 -> cycle 2p, lanes 32-63 -> cycle 2p+1.
// R2 change under test: REGULAR store instead of nontemporal. Both prior
// expand variants (different layouts/prefetch) measured identically ~118 us
// = 256 MB / 2.17 TB/s -> pattern-insensitive NT-store ceiling suspected;
// fillBufferAligned proves 6.5 TB/s for regular full-line stores.
__global__ __launch_bounds__(256) void expand2_kernel(
        const unsigned char* __restrict__ cnt,
        const float* __restrict__ emb,
        float* __restrict__ out,
        int num_cycles) {
    __shared__ __align__(16) float lds[NTYPES * H];
    for (int i = threadIdx.x; i < NTYPES * H; i += blockDim.x) lds[i] = emb[i];
    __syncthreads();
    const f32x4* l4 = (const f32x4*)lds;

    const int lane = threadIdx.x & 63;
    const int half = lane >> 5;
    const int hl   = lane & 31;
    const int w    = blockIdx.x * (blockDim.x >> 6) + (threadIdx.x >> 6);
    const int nw   = gridDim.x * (blockDim.x >> 6);

    const int P   = (num_cycles + 1) >> 1;        // cycle pairs
    const int ppw = (P + nw - 1) / nw;            // pairs per wave (contiguous)
    int p0 = w * ppw;
    int p1 = p0 + ppw; if (p1 > P) p1 = P;
    if (p0 >= p1) return;

    // depth-2 prefetch of the 64 B counter line (1 byte/lane)
    unsigned b0 = cnt[(size_t)p0 * 64 + lane];
    unsigned b1 = (p0 + 1 < p1) ? cnt[(size_t)(p0 + 1) * 64 + lane] : 0u;

    for (int p = p0; p < p1; ++p) {
        unsigned b = b0;
        b0 = b1;
        b1 = (p + 2 < p1) ? cnt[(size_t)(p + 2) * 64 + lane] : 0u;

        int c = 2 * p + half;
        unsigned long long bal = __ballot(b != 0);
        unsigned m = (half ? (unsigned)(bal >> 32) : (unsigned)bal) & 0x0FFFFFFFu;
        if (c >= num_cycles) m = 0;               // odd-tail guard (garbage half)

        f32x4 acc = {0.f, 0.f, 0.f, 0.f};
        while (m) {                               // iters = max(pop(m0),pop(m1)) ~ 5
            int t = __builtin_ctz(m);
            m &= m - 1;
            float f = (float)(unsigned)__shfl((int)b, t + (half << 5));
            f32x4 wv = l4[t * 32 + hl];           // ds_read_b128, conflict-free
            acc += f * wv;
        }
        if (c < num_cycles) {
            // full 64 B lines per wave (1 KB contiguous): no RFO; regular
            // store path measured at 6.5 TB/s by the harness fill.
            f32x4* dst = (f32x4*)(out + (size_t)c * H) + hl;
            *dst = acc;
        }
    }
}

// ---- fallback (ws too small): direct atomic scatter ----
__global__ void scatter_direct_kernel(const int* __restrict__ a2c,
                                      const int* __restrict__ x,
                                      const float* __restrict__ emb,
                                      float* __restrict__ out,
                                      int n_inc) {
    int gid = blockIdx.x * blockDim.x + threadIdx.x;
    int e  = gid >> 5;
    int ch = gid & 31;
    if (e >= n_inc) return;
    int atom = a2c[e];
    int cyc  = a2c[n_inc + e];
    int t    = x[atom];
    const float4 w = ((const float4*)(emb + t * H))[ch];
    float* o = out + (size_t)cyc * H + ch * 4;
    atomicAdd(o + 0, w.x);
    atomicAdd(o + 1, w.y);
    atomicAdd(o + 2, w.z);
    atomicAdd(o + 3, w.w);
}

__global__ void zero_u4_kernel(uint4* __restrict__ p, int n4) {
    int i = blockIdx.x * blockDim.x + threadIdx.x;
    if (i < n4) p[i] = make_uint4(0u, 0u, 0u, 0u);
}

extern "C" void kernel_launch(void* const* d_in, const int* in_sizes, int n_in,
                              void* d_out, int out_size, void* d_ws, size_t ws_size,
                              hipStream_t stream) {
    const int*   x    = (const int*)d_in[0];
    const int*   a2c  = (const int*)d_in[1];
    const float* emb  = (const float*)d_in[2];
    float*       out  = (float*)d_out;

    const int n_inc      = in_sizes[1] / 2;
    const int num_cycles = out_size / H;
    const size_t cnt_bytes = (size_t)num_cycles * CNT_BYTES_PER_CYCLE;

    if (ws_size >= cnt_bytes) {
        unsigned* cnt = (unsigned*)d_ws;
        hipMemsetAsync(d_ws, 0, cnt_bytes, stream);
        int nthreads = (n_inc + 3) / 4;
        count_kernel<<<(nthreads + 255) / 256, 256, 0, stream>>>(a2c, x, cnt, n_inc);
        // 2048 blocks x 256 threads = 8192 waves: full residency at 32 waves/CU
        expand2_kernel<<<2048, 256, 0, stream>>>(
            (const unsigned char*)cnt, emb, out, num_cycles);
    } else {
        int n4 = out_size / 4;
        zero_u4_kernel<<<(n4 + 255) / 256, 256, 0, stream>>>((uint4*)d_out, n4);
        long long total = (long long)n_inc * 32;
        int blocks = (int)((total + 255) / 256);
        scatter_direct_kernel<<<blocks, 256, 0, stream>>>(a2c, x, emb, out, n_inc);
    }
}